// Round 1
// baseline (724.205 us; speedup 1.0000x reference)
//
#include <hip/hip_runtime.h>
#include <math.h>

#define HH 384
#define WW 384
#define NG 16
#define CPG 3
#define CC (NG*CPG)   // 48 trunk channels
#define TW 64
#define TH 4

// ---------------------------------------------------------------------------
// Layer 1: x = data - 3.5 ; h = relu(gconv(x, w1*maskA, b1))
// maskA taps: rows 0,1 all 5 cols; row 2 cols 0,1  (dy=r-2, dx=c-2)
// ---------------------------------------------------------------------------
__global__ __launch_bounds__(256) void conv1_kernel(
    const int* __restrict__ data, const float* __restrict__ w1,
    const float* __restrict__ b1, float* __restrict__ h)
{
    const int g  = blockIdx.z;
    const int x0 = blockIdx.x * TW, y0 = blockIdx.y * TH;
    __shared__ float s_in[TH + 2][TW + 4];
    __shared__ float s_w[3][25];
    __shared__ float s_b[3];
    const int tid = threadIdx.y * TW + threadIdx.x;

    for (int i = tid; i < 75; i += 256)
        s_w[i / 25][i % 25] = w1[(g * 3 + i / 25) * 25 + i % 25];
    if (tid < 3) s_b[tid] = b1[g * 3 + tid];

    const int* plane = data + g * HH * WW;
    for (int i = tid; i < (TH + 2) * (TW + 4); i += 256) {
        int rr = i / (TW + 4), cc = i % (TW + 4);
        int gy = y0 + rr - 2, gx = x0 + cc - 2;
        float v = 0.f;
        if (gy >= 0 && gx >= 0 && gx < WW)
            v = (float)plane[gy * WW + gx] - 3.5f;
        s_in[rr][cc] = v;
    }
    __syncthreads();

    const int tx = threadIdx.x, ty = threadIdx.y;
    float a0 = s_b[0], a1 = s_b[1], a2 = s_b[2];
#pragma unroll
    for (int r = 0; r < 3; ++r) {
        const int cmax = (r < 2) ? 5 : 2;
#pragma unroll
        for (int c = 0; c < 5; ++c) {
            if (c >= cmax) break;
            float v = s_in[ty + r][tx + c];
            a0 += v * s_w[0][r * 5 + c];
            a1 += v * s_w[1][r * 5 + c];
            a2 += v * s_w[2][r * 5 + c];
        }
    }
    const int y = y0 + ty, x = x0 + tx;
    int o = (g * 3) * HH * WW + y * WW + x;
    h[o]              = fmaxf(a0, 0.f);
    h[o + HH * WW]     = fmaxf(a1, 0.f);
    h[o + 2 * HH * WW] = fmaxf(a2, 0.f);
}

// ---------------------------------------------------------------------------
// Residual conv (mask B: rows 0,1 all; row 2 cols 0,1,2).
// ADD=false: out = relu(conv(in)) ; ADD=true: out += relu(conv(in))
// ---------------------------------------------------------------------------
template <bool ADD>
__global__ __launch_bounds__(256) void convB_kernel(
    const float* __restrict__ in, const float* __restrict__ w,
    const float* __restrict__ b, float* __restrict__ out)
{
    const int g  = blockIdx.z;
    const int x0 = blockIdx.x * TW, y0 = blockIdx.y * TH;
    __shared__ float s_in[3][TH + 2][TW + 4];
    __shared__ float s_w[3][3][25];
    __shared__ float s_b[3];
    const int tid = threadIdx.y * TW + threadIdx.x;

    for (int i = tid; i < 225; i += 256) {
        int oc = i / 75, rest = i % 75;
        s_w[oc][rest / 25][rest % 25] =
            w[((g * 3 + oc) * 3 + rest / 25) * 25 + rest % 25];
    }
    if (tid < 3) s_b[tid] = b[g * 3 + tid];

    const float* base = in + (size_t)g * 3 * HH * WW;
    const int cpl = (TH + 2) * (TW + 4);
    for (int i = tid; i < 3 * cpl; i += 256) {
        int ch = i / cpl, rr = (i % cpl) / (TW + 4), cc = i % (TW + 4);
        int gy = y0 + rr - 2, gx = x0 + cc - 2;
        float v = 0.f;
        if (gy >= 0 && gx >= 0 && gx < WW)
            v = base[ch * HH * WW + gy * WW + gx];
        s_in[ch][rr][cc] = v;
    }
    __syncthreads();

    const int tx = threadIdx.x, ty = threadIdx.y;
    float a0 = s_b[0], a1 = s_b[1], a2 = s_b[2];
#pragma unroll
    for (int ic = 0; ic < 3; ++ic) {
#pragma unroll
        for (int r = 0; r < 3; ++r) {
            const int cmax = (r < 2) ? 5 : 3;
#pragma unroll
            for (int c = 0; c < 5; ++c) {
                if (c >= cmax) break;
                float v = s_in[ic][ty + r][tx + c];
                a0 += v * s_w[0][ic][r * 5 + c];
                a1 += v * s_w[1][ic][r * 5 + c];
                a2 += v * s_w[2][ic][r * 5 + c];
            }
        }
    }
    const int y = y0 + ty, x = x0 + tx;
    int o = (g * 3) * HH * WW + y * WW + x;
    float v0 = fmaxf(a0, 0.f), v1 = fmaxf(a1, 0.f), v2 = fmaxf(a2, 0.f);
    if (ADD) {
        out[o]              += v0;
        out[o + HH * WW]     += v1;
        out[o + 2 * HH * WW] += v2;
    } else {
        out[o]              = v0;
        out[o + HH * WW]     = v1;
        out[o + 2 * HH * WW] = v2;
    }
}

// ---------------------------------------------------------------------------
// Final conv (9 outputs per group) fused with mixture-CDF -> pmf * 65536
// ---------------------------------------------------------------------------
__device__ __forceinline__ float softplus_f(float x) {
    return (x > 0.f) ? x + log1pf(expf(-x)) : log1pf(expf(x));
}

__global__ __launch_bounds__(256) void final_kernel(
    const float* __restrict__ hbuf, const float* __restrict__ wf,
    const float* __restrict__ bf, float* __restrict__ out)
{
    const int g  = blockIdx.z;
    const int x0 = blockIdx.x * TW, y0 = blockIdx.y * TH;
    __shared__ float s_in[3][TH + 2][TW + 4];
    __shared__ float s_w[9][3][25];
    __shared__ float s_b[9];
    const int tid = threadIdx.y * TW + threadIdx.x;

    for (int i = tid; i < 675; i += 256) {
        int oc = i / 75, rest = i % 75;
        s_w[oc][rest / 25][rest % 25] =
            wf[((g * 9 + oc) * 3 + rest / 25) * 25 + rest % 25];
    }
    if (tid < 9) s_b[tid] = bf[g * 9 + tid];

    const float* base = hbuf + (size_t)g * 3 * HH * WW;
    const int cpl = (TH + 2) * (TW + 4);
    for (int i = tid; i < 3 * cpl; i += 256) {
        int ch = i / cpl, rr = (i % cpl) / (TW + 4), cc = i % (TW + 4);
        int gy = y0 + rr - 2, gx = x0 + cc - 2;
        float v = 0.f;
        if (gy >= 0 && gx >= 0 && gx < WW)
            v = base[ch * HH * WW + gy * WW + gx];
        s_in[ch][rr][cc] = v;
    }
    __syncthreads();

    const int tx = threadIdx.x, ty = threadIdx.y;
    float acc[9];
#pragma unroll
    for (int m = 0; m < 9; ++m) acc[m] = s_b[m];
#pragma unroll
    for (int ic = 0; ic < 3; ++ic) {
#pragma unroll
        for (int r = 0; r < 3; ++r) {
            const int cmax = (r < 2) ? 5 : 3;
#pragma unroll
            for (int c = 0; c < 5; ++c) {
                if (c >= cmax) break;
                float v = s_in[ic][ty + r][tx + c];
#pragma unroll
                for (int m = 0; m < 9; ++m)
                    acc[m] += v * s_w[m][ic][r * 5 + c];
            }
        }
    }

    // mixture: channel m = mix*3 + param
    const float lw0 = acc[0], mu0 = acc[1], ls0 = acc[2];
    const float lw1 = acc[3], mu1 = acc[4], ls1 = acc[5];
    const float lw2 = acc[6], mu2 = acc[7], ls2 = acc[8];

    float lmax = fmaxf(lw0, fmaxf(lw1, lw2));
    float e0 = expf(lw0 - lmax), e1 = expf(lw1 - lmax), e2 = expf(lw2 - lmax);
    float inv_sum = 1.f / (e0 + e1 + e2);
    float wm0 = e0 * inv_sum, wm1 = e1 * inv_sum, wm2 = e2 * inv_sum;

    const float inv_sqrt2 = 0.70710678118654752440f;
    float k0 = inv_sqrt2 / (softplus_f(ls0) + 1e-6f);
    float k1 = inv_sqrt2 / (softplus_f(ls1) + 1e-6f);
    float k2 = inv_sqrt2 / (softplus_f(ls2) + 1e-6f);

    const int y = y0 + ty, x = x0 + tx;
    float prev = 0.f;
#pragma unroll
    for (int j = 0; j <= 8; ++j) {
        float edge = (float)j - 4.0f;
        float cdf = wm0 * 0.5f * (1.f + erff((edge - mu0) * k0))
                  + wm1 * 0.5f * (1.f + erff((edge - mu1) * k1))
                  + wm2 * 0.5f * (1.f + erff((edge - mu2) * k2));
        if (j > 0)
            out[((g * 8 + (j - 1)) * HH + y) * WW + x] = (cdf - prev) * 65536.f;
        prev = cdf;
    }
}

// ---------------------------------------------------------------------------
extern "C" void kernel_launch(void* const* d_in, const int* in_sizes, int n_in,
                              void* d_out, int out_size, void* d_ws, size_t ws_size,
                              hipStream_t stream)
{
    const int*   data = (const int*)d_in[0];
    const float* w1   = (const float*)d_in[1];
    const float* b1   = (const float*)d_in[2];
    const float* rw   = (const float*)d_in[3];
    const float* rb   = (const float*)d_in[4];
    const float* wf   = (const float*)d_in[5];
    const float* bf   = (const float*)d_in[6];
    float* out = (float*)d_out;

    float* h = (float*)d_ws;
    float* t = h + (size_t)CC * HH * WW;

    dim3 blk(TW, TH, 1);
    dim3 grd(WW / TW, HH / TH, NG);

    conv1_kernel<<<grd, blk, 0, stream>>>(data, w1, b1, h);
    for (int i = 0; i < 5; ++i) {
        const float* wa = rw + (size_t)(i * 2 + 0) * CC * 3 * 25;
        const float* ba = rb + (i * 2 + 0) * CC;
        const float* wb = rw + (size_t)(i * 2 + 1) * CC * 3 * 25;
        const float* bb = rb + (i * 2 + 1) * CC;
        convB_kernel<false><<<grd, blk, 0, stream>>>(h, wa, ba, t);
        convB_kernel<true ><<<grd, blk, 0, stream>>>(t, wb, bb, h);
    }
    final_kernel<<<grd, blk, 0, stream>>>(h, wf, bf, out);
}

// Round 2
// 448.931 us; speedup vs baseline: 1.6132x; 1.6132x over previous
//
#include <hip/hip_runtime.h>
#include <math.h>

#define HH 384
#define WW 384
#define NG 16
#define CPG 3
#define CC (NG*CPG)   // 48 trunk channels
#define TW 64
#define TH 4

// ---------------------------------------------------------------------------
// Layer 1: x = data - 3.5 ; h = relu(gconv(x, w1*maskA, b1))
// maskA taps: rows 0,1 all 5 cols; row 2 cols 0,1  (dy=r-2, dx=c-2)
// ---------------------------------------------------------------------------
__global__ __launch_bounds__(256) void conv1_kernel(
    const int* __restrict__ data, const float* __restrict__ w1,
    const float* __restrict__ b1, float* __restrict__ h)
{
    const int g  = blockIdx.z;
    const int x0 = blockIdx.x * TW, y0 = blockIdx.y * TH;
    __shared__ float s_in[TH + 2][TW + 4];
    __shared__ float s_w[3][25];
    __shared__ float s_b[3];
    const int tid = threadIdx.y * TW + threadIdx.x;

    for (int i = tid; i < 75; i += 256)
        s_w[i / 25][i % 25] = w1[(g * 3 + i / 25) * 25 + i % 25];
    if (tid < 3) s_b[tid] = b1[g * 3 + tid];

    const int* plane = data + g * HH * WW;
    for (int i = tid; i < (TH + 2) * (TW + 4); i += 256) {
        int rr = i / (TW + 4), cc = i % (TW + 4);
        int gy = y0 + rr - 2, gx = x0 + cc - 2;
        float v = 0.f;
        if (gy >= 0 && gx >= 0 && gx < WW)
            v = (float)plane[gy * WW + gx] - 3.5f;
        s_in[rr][cc] = v;
    }
    __syncthreads();

    const int tx = threadIdx.x, ty = threadIdx.y;
    float a0 = s_b[0], a1 = s_b[1], a2 = s_b[2];
#pragma unroll
    for (int r = 0; r < 3; ++r) {
        const int cmax = (r < 2) ? 5 : 2;
#pragma unroll
        for (int c = 0; c < 5; ++c) {
            if (c >= cmax) break;
            float v = s_in[ty + r][tx + c];
            a0 += v * s_w[0][r * 5 + c];
            a1 += v * s_w[1][r * 5 + c];
            a2 += v * s_w[2][r * 5 + c];
        }
    }
    const int y = y0 + ty, x = x0 + tx;
    int o = (g * 3) * HH * WW + y * WW + x;
    h[o]              = fmaxf(a0, 0.f);
    h[o + HH * WW]     = fmaxf(a1, 0.f);
    h[o + 2 * HH * WW] = fmaxf(a2, 0.f);
}

// ---------------------------------------------------------------------------
// Residual conv (mask B: rows 0,1 all; row 2 cols 0,1,2).
// ADD=false: out = relu(conv(in)) ; ADD=true: out += relu(conv(in))
// ---------------------------------------------------------------------------
template <bool ADD>
__global__ __launch_bounds__(256) void convB_kernel(
    const float* __restrict__ in, const float* __restrict__ w,
    const float* __restrict__ b, float* __restrict__ out)
{
    const int g  = blockIdx.z;
    const int x0 = blockIdx.x * TW, y0 = blockIdx.y * TH;
    __shared__ float s_in[3][TH + 2][TW + 4];
    __shared__ float s_w[3][3][25];
    __shared__ float s_b[3];
    const int tid = threadIdx.y * TW + threadIdx.x;

    for (int i = tid; i < 225; i += 256) {
        int oc = i / 75, rest = i % 75;
        s_w[oc][rest / 25][rest % 25] =
            w[((g * 3 + oc) * 3 + rest / 25) * 25 + rest % 25];
    }
    if (tid < 3) s_b[tid] = b[g * 3 + tid];

    const float* base = in + (size_t)g * 3 * HH * WW;
    const int cpl = (TH + 2) * (TW + 4);
    for (int i = tid; i < 3 * cpl; i += 256) {
        int ch = i / cpl, rr = (i % cpl) / (TW + 4), cc = i % (TW + 4);
        int gy = y0 + rr - 2, gx = x0 + cc - 2;
        float v = 0.f;
        if (gy >= 0 && gx >= 0 && gx < WW)
            v = base[ch * HH * WW + gy * WW + gx];
        s_in[ch][rr][cc] = v;
    }
    __syncthreads();

    const int tx = threadIdx.x, ty = threadIdx.y;
    float a0 = s_b[0], a1 = s_b[1], a2 = s_b[2];
#pragma unroll
    for (int ic = 0; ic < 3; ++ic) {
#pragma unroll
        for (int r = 0; r < 3; ++r) {
            const int cmax = (r < 2) ? 5 : 3;
#pragma unroll
            for (int c = 0; c < 5; ++c) {
                if (c >= cmax) break;
                float v = s_in[ic][ty + r][tx + c];
                a0 += v * s_w[0][ic][r * 5 + c];
                a1 += v * s_w[1][ic][r * 5 + c];
                a2 += v * s_w[2][ic][r * 5 + c];
            }
        }
    }
    const int y = y0 + ty, x = x0 + tx;
    int o = (g * 3) * HH * WW + y * WW + x;
    float v0 = fmaxf(a0, 0.f), v1 = fmaxf(a1, 0.f), v2 = fmaxf(a2, 0.f);
    if (ADD) {
        out[o]              += v0;
        out[o + HH * WW]     += v1;
        out[o + 2 * HH * WW] += v2;
    } else {
        out[o]              = v0;
        out[o + HH * WW]     = v1;
        out[o + 2 * HH * WW] = v2;
    }
}

// ---------------------------------------------------------------------------
// Fast branchless transcendentals (hardware v_exp/v_rcp/v_sqrt based)
// ---------------------------------------------------------------------------
__device__ __forceinline__ float fast_rcp(float x) {
    return __builtin_amdgcn_rcpf(x);
}

// Winitzki erf approximation, max abs err ~1.3e-4 (output tolerance is 947/65536
// = 1.4e-2 in cdf units -> 100x margin).
__device__ __forceinline__ float fast_erf(float x) {
    const float a = 0.147f;
    const float c = 1.27323954f;  // 4/pi
    float x2 = x * x;
    float ax2 = a * x2;
    float t = x2 * (c + ax2) * fast_rcp(1.f + ax2);
    float e = __expf(-t);
    float s = __builtin_amdgcn_sqrtf(fmaxf(1.f - e, 0.f));
    return copysignf(s, x);
}

// softplus; relative sloppiness for very negative x is harmless (enters only
// via 1/(softplus+1e-6); cdf saturates identically).
__device__ __forceinline__ float fast_softplus(float x) {
    float t = __expf(-fabsf(x));
    return fmaxf(x, 0.f) + __logf(1.f + t);
}

// ---------------------------------------------------------------------------
// Final conv (9 outputs per group) fused with mixture-CDF -> pmf * 65536
// ---------------------------------------------------------------------------
__global__ __launch_bounds__(256) void final_kernel(
    const float* __restrict__ hbuf, const float* __restrict__ wf,
    const float* __restrict__ bf, float* __restrict__ out)
{
    const int g  = blockIdx.z;
    const int x0 = blockIdx.x * TW, y0 = blockIdx.y * TH;
    __shared__ float s_in[3][TH + 2][TW + 4];
    __shared__ float s_w[9][3][25];
    __shared__ float s_b[9];
    const int tid = threadIdx.y * TW + threadIdx.x;

    for (int i = tid; i < 675; i += 256) {
        int oc = i / 75, rest = i % 75;
        s_w[oc][rest / 25][rest % 25] =
            wf[((g * 9 + oc) * 3 + rest / 25) * 25 + rest % 25];
    }
    if (tid < 9) s_b[tid] = bf[g * 9 + tid];

    const float* base = hbuf + (size_t)g * 3 * HH * WW;
    const int cpl = (TH + 2) * (TW + 4);
    for (int i = tid; i < 3 * cpl; i += 256) {
        int ch = i / cpl, rr = (i % cpl) / (TW + 4), cc = i % (TW + 4);
        int gy = y0 + rr - 2, gx = x0 + cc - 2;
        float v = 0.f;
        if (gy >= 0 && gx >= 0 && gx < WW)
            v = base[ch * HH * WW + gy * WW + gx];
        s_in[ch][rr][cc] = v;
    }
    __syncthreads();

    const int tx = threadIdx.x, ty = threadIdx.y;
    float acc[9];
#pragma unroll
    for (int m = 0; m < 9; ++m) acc[m] = s_b[m];
#pragma unroll
    for (int ic = 0; ic < 3; ++ic) {
#pragma unroll
        for (int r = 0; r < 3; ++r) {
            const int cmax = (r < 2) ? 5 : 3;
#pragma unroll
            for (int c = 0; c < 5; ++c) {
                if (c >= cmax) break;
                float v = s_in[ic][ty + r][tx + c];
#pragma unroll
                for (int m = 0; m < 9; ++m)
                    acc[m] += v * s_w[m][ic][r * 5 + c];
            }
        }
    }

    // mixture: channel m = mix*3 + param
    const float lw0 = acc[0], mu0 = acc[1], ls0 = acc[2];
    const float lw1 = acc[3], mu1 = acc[4], ls1 = acc[5];
    const float lw2 = acc[6], mu2 = acc[7], ls2 = acc[8];

    float lmax = fmaxf(lw0, fmaxf(lw1, lw2));
    float e0 = __expf(lw0 - lmax), e1 = __expf(lw1 - lmax), e2 = __expf(lw2 - lmax);
    float inv_sum = fast_rcp(e0 + e1 + e2);
    float wm0 = 0.5f * e0 * inv_sum, wm1 = 0.5f * e1 * inv_sum, wm2 = 0.5f * e2 * inv_sum;

    const float inv_sqrt2 = 0.70710678118654752440f;
    float k0 = inv_sqrt2 * fast_rcp(fast_softplus(ls0) + 1e-6f);
    float k1 = inv_sqrt2 * fast_rcp(fast_softplus(ls1) + 1e-6f);
    float k2 = inv_sqrt2 * fast_rcp(fast_softplus(ls2) + 1e-6f);

    const int y = y0 + ty, x = x0 + tx;
    float* optr = out + ((size_t)g * 8 * HH + y) * WW + x;
    float prev = 0.f;
#pragma unroll
    for (int j = 0; j <= 8; ++j) {
        float edge = (float)j - 4.0f;
        float cdf = wm0 * (1.f + fast_erf((edge - mu0) * k0))
                  + wm1 * (1.f + fast_erf((edge - mu1) * k1))
                  + wm2 * (1.f + fast_erf((edge - mu2) * k2));
        if (j > 0) {
            optr[(size_t)(j - 1) * HH * WW] = (cdf - prev) * 65536.f;
        }
        prev = cdf;
    }
}

// ---------------------------------------------------------------------------
extern "C" void kernel_launch(void* const* d_in, const int* in_sizes, int n_in,
                              void* d_out, int out_size, void* d_ws, size_t ws_size,
                              hipStream_t stream)
{
    const int*   data = (const int*)d_in[0];
    const float* w1   = (const float*)d_in[1];
    const float* b1   = (const float*)d_in[2];
    const float* rw   = (const float*)d_in[3];
    const float* rb   = (const float*)d_in[4];
    const float* wf   = (const float*)d_in[5];
    const float* bf   = (const float*)d_in[6];
    float* out = (float*)d_out;

    float* h = (float*)d_ws;
    float* t = h + (size_t)CC * HH * WW;

    dim3 blk(TW, TH, 1);
    dim3 grd(WW / TW, HH / TH, NG);

    conv1_kernel<<<grd, blk, 0, stream>>>(data, w1, b1, h);
    for (int i = 0; i < 5; ++i) {
        const float* wa = rw + (size_t)(i * 2 + 0) * CC * 3 * 25;
        const float* ba = rb + (i * 2 + 0) * CC;
        const float* wb = rw + (size_t)(i * 2 + 1) * CC * 3 * 25;
        const float* bb = rb + (i * 2 + 1) * CC;
        convB_kernel<false><<<grd, blk, 0, stream>>>(h, wa, ba, t);
        convB_kernel<true ><<<grd, blk, 0, stream>>>(t, wb, bb, h);
    }
    final_kernel<<<grd, blk, 0, stream>>>(h, wf, bf, out);
}

// Round 3
// 334.882 us; speedup vs baseline: 2.1626x; 1.3406x over previous
//
#include <hip/hip_runtime.h>
#include <math.h>

#define HH 384
#define WW 384
#define NG 16
#define HW (HH*WW)

// fused tiles: 64 wide x 16 tall, 256 threads = (16 xg, 16 y), 4 px/thread
#define FTW 64
#define FTH 16

// ---------------------------------------------------------------------------
// Layer 1: x = data - 3.5 ; h = relu(gconv(x, w1*maskA, b1))
// maskA taps: rows 0,1 all 5 cols; row 2 cols 0,1
// ---------------------------------------------------------------------------
__global__ __launch_bounds__(256) void conv1_kernel(
    const int* __restrict__ data, const float* __restrict__ w1,
    const float* __restrict__ b1, float* __restrict__ h)
{
    const int g  = blockIdx.z;
    const int x0 = blockIdx.x * 64, y0 = blockIdx.y * 4;
    __shared__ float s_in[4 + 2][64 + 4];
    __shared__ float s_w[3][25];
    __shared__ float s_b[3];
    const int tid = threadIdx.y * 64 + threadIdx.x;

    for (int i = tid; i < 75; i += 256)
        s_w[i / 25][i % 25] = w1[(g * 3 + i / 25) * 25 + i % 25];
    if (tid < 3) s_b[tid] = b1[g * 3 + tid];

    const int* plane = data + g * HW;
    for (int i = tid; i < 6 * 68; i += 256) {
        int rr = i / 68, cc = i % 68;
        int gy = y0 + rr - 2, gx = x0 + cc - 2;
        float v = 0.f;
        if (gy >= 0 && gx >= 0 && gx < WW)
            v = (float)plane[gy * WW + gx] - 3.5f;
        s_in[rr][cc] = v;
    }
    __syncthreads();

    const int tx = threadIdx.x, ty = threadIdx.y;
    float a0 = s_b[0], a1 = s_b[1], a2 = s_b[2];
#pragma unroll
    for (int r = 0; r < 3; ++r) {
        const int cmax = (r < 2) ? 5 : 2;
#pragma unroll
        for (int c = 0; c < 5; ++c) {
            if (c >= cmax) break;
            float v = s_in[ty + r][tx + c];
            a0 += v * s_w[0][r * 5 + c];
            a1 += v * s_w[1][r * 5 + c];
            a2 += v * s_w[2][r * 5 + c];
        }
    }
    const int y = y0 + ty, x = x0 + tx;
    int o = (g * 3) * HW + y * WW + x;
    h[o]          = fmaxf(a0, 0.f);
    h[o + HW]     = fmaxf(a1, 0.f);
    h[o + 2 * HW] = fmaxf(a2, 0.f);
}

// ---------------------------------------------------------------------------
// Fused residual block: out = in + relu(convB(relu(convB(in, wa)), wb))
// Tile FTHxFTW. IN origin (y0-4, x0-4), dims (FTH+4)x(FTW+8).
// T (intermediate) origin (y0-2, x0-2), dims (FTH+2)x(FTW+4).
// maskB taps: rows 0,1 all 5 cols; row 2 cols 0..2.
// ---------------------------------------------------------------------------
__global__ __launch_bounds__(256) void res_block_kernel(
    const float* __restrict__ in, const float* __restrict__ wa,
    const float* __restrict__ ba, const float* __restrict__ wb,
    const float* __restrict__ bb, float* __restrict__ out)
{
    const int g  = blockIdx.z;
    const int x0 = blockIdx.x * FTW, y0 = blockIdx.y * FTH;
    __shared__ __align__(16) float IN[3][FTH + 4][FTW + 8];
    __shared__ __align__(16) float T [3][FTH + 2][FTW + 4];
    __shared__ float s_wa[3][3][25], s_wb[3][3][25];
    __shared__ float s_ba[3], s_bb[3];
    const int tid = threadIdx.y * 16 + threadIdx.x;

    for (int i = tid; i < 450; i += 256) {
        int k = i % 225, oc = k / 75, rest = k % 75;
        if (i < 225)
            s_wa[oc][rest / 25][rest % 25] = wa[((g * 3 + oc) * 3 + rest / 25) * 25 + rest % 25];
        else
            s_wb[oc][rest / 25][rest % 25] = wb[((g * 3 + oc) * 3 + rest / 25) * 25 + rest % 25];
    }
    if (tid < 3) s_ba[tid] = ba[g * 3 + tid];
    else if (tid < 6) s_bb[tid - 3] = bb[g * 3 + tid - 3];

    // ---- stage input tile (zero-padded), float4 fast path ----
    const float* base = in + (size_t)g * 3 * HW;
    for (int i = tid; i < 3 * (FTH + 4) * ((FTW + 8) / 4); i += 256) { // 1080
        int ch = i / 360, rem = i % 360, rr = rem / 18, q = rem % 18;
        int gy = y0 - 4 + rr, gx0 = x0 - 4 + 4 * q;
        float4 v = make_float4(0.f, 0.f, 0.f, 0.f);
        if (gy >= 0) {
            const float* rowp = base + (size_t)ch * HW + (size_t)gy * WW;
            if (gx0 >= 0 && gx0 + 3 < WW) {
                v = *(const float4*)(rowp + gx0);
            } else {
                float t[4];
#pragma unroll
                for (int p = 0; p < 4; ++p) {
                    int gx = gx0 + p;
                    t[p] = (gx >= 0 && gx < WW) ? rowp[gx] : 0.f;
                }
                v = make_float4(t[0], t[1], t[2], t[3]);
            }
        }
        *(float4*)&IN[ch][rr][4 * q] = v;
    }
    __syncthreads();

    // ---- first conv: T = relu(convB(IN)), on (FTH+2)x(FTW+4) region ----
    for (int i = tid; i < (FTH + 2) * ((FTW + 4) / 4); i += 256) {  // 306
        int ty = i / 17, q = i % 17, tx0 = 4 * q;
        int gty = y0 - 2 + ty, gtx0 = x0 - 2 + tx0;
        float a0[4], a1[4], a2[4];
#pragma unroll
        for (int p = 0; p < 4; ++p) { a0[p] = s_ba[0]; a1[p] = s_ba[1]; a2[p] = s_ba[2]; }
#pragma unroll
        for (int ic = 0; ic < 3; ++ic) {
#pragma unroll
            for (int r = 0; r < 3; ++r) {
                float4 u0 = *(const float4*)&IN[ic][ty + r][tx0];
                float4 u1 = *(const float4*)&IN[ic][ty + r][tx0 + 4];
                float v[8] = {u0.x, u0.y, u0.z, u0.w, u1.x, u1.y, u1.z, u1.w};
                const int cmax = (r < 2) ? 5 : 3;
#pragma unroll
                for (int c = 0; c < 5; ++c) {
                    if (c >= cmax) break;
                    float w0 = s_wa[0][ic][r * 5 + c];
                    float w1 = s_wa[1][ic][r * 5 + c];
                    float w2 = s_wa[2][ic][r * 5 + c];
#pragma unroll
                    for (int p = 0; p < 4; ++p) {
                        a0[p] += w0 * v[c + p];
                        a1[p] += w1 * v[c + p];
                        a2[p] += w2 * v[c + p];
                    }
                }
            }
        }
        float r0[4], r1[4], r2[4];
#pragma unroll
        for (int p = 0; p < 4; ++p) {
            int gx = gtx0 + p;
            bool ok = (gty >= 0) && (gx >= 0) && (gx < WW);
            r0[p] = ok ? fmaxf(a0[p], 0.f) : 0.f;
            r1[p] = ok ? fmaxf(a1[p], 0.f) : 0.f;
            r2[p] = ok ? fmaxf(a2[p], 0.f) : 0.f;
        }
        *(float4*)&T[0][ty][tx0] = make_float4(r0[0], r0[1], r0[2], r0[3]);
        *(float4*)&T[1][ty][tx0] = make_float4(r1[0], r1[1], r1[2], r1[3]);
        *(float4*)&T[2][ty][tx0] = make_float4(r2[0], r2[1], r2[2], r2[3]);
    }
    __syncthreads();

    // ---- second conv + residual add + write ----
    const int xg = threadIdx.x, yy = threadIdx.y;
    float a0[4], a1[4], a2[4];
#pragma unroll
    for (int p = 0; p < 4; ++p) { a0[p] = s_bb[0]; a1[p] = s_bb[1]; a2[p] = s_bb[2]; }
#pragma unroll
    for (int ic = 0; ic < 3; ++ic) {
#pragma unroll
        for (int r = 0; r < 3; ++r) {
            float4 u0 = *(const float4*)&T[ic][yy + r][4 * xg];
            float4 u1 = *(const float4*)&T[ic][yy + r][4 * xg + 4];
            float v[8] = {u0.x, u0.y, u0.z, u0.w, u1.x, u1.y, u1.z, u1.w};
            const int cmax = (r < 2) ? 5 : 3;
#pragma unroll
            for (int c = 0; c < 5; ++c) {
                if (c >= cmax) break;
                float w0 = s_wb[0][ic][r * 5 + c];
                float w1 = s_wb[1][ic][r * 5 + c];
                float w2 = s_wb[2][ic][r * 5 + c];
#pragma unroll
                for (int p = 0; p < 4; ++p) {
                    a0[p] += w0 * v[c + p];
                    a1[p] += w1 * v[c + p];
                    a2[p] += w2 * v[c + p];
                }
            }
        }
    }
    const int gy = y0 + yy;
    float* ob = out + (size_t)g * 3 * HW + (size_t)gy * WW + x0 + 4 * xg;
    float4 h0 = *(const float4*)&IN[0][yy + 4][4 * xg + 4];
    float4 h1 = *(const float4*)&IN[1][yy + 4][4 * xg + 4];
    float4 h2 = *(const float4*)&IN[2][yy + 4][4 * xg + 4];
    *(float4*)(ob)          = make_float4(h0.x + fmaxf(a0[0],0.f), h0.y + fmaxf(a0[1],0.f),
                                          h0.z + fmaxf(a0[2],0.f), h0.w + fmaxf(a0[3],0.f));
    *(float4*)(ob + HW)     = make_float4(h1.x + fmaxf(a1[0],0.f), h1.y + fmaxf(a1[1],0.f),
                                          h1.z + fmaxf(a1[2],0.f), h1.w + fmaxf(a1[3],0.f));
    *(float4*)(ob + 2*HW)   = make_float4(h2.x + fmaxf(a2[0],0.f), h2.y + fmaxf(a2[1],0.f),
                                          h2.z + fmaxf(a2[2],0.f), h2.w + fmaxf(a2[3],0.f));
}

// ---------------------------------------------------------------------------
// Fast branchless transcendentals
// ---------------------------------------------------------------------------
__device__ __forceinline__ float fast_rcp(float x) {
    return __builtin_amdgcn_rcpf(x);
}

// Winitzki erf approximation, max abs err ~1.3e-4
__device__ __forceinline__ float fast_erf(float x) {
    const float a = 0.147f;
    const float c = 1.27323954f;  // 4/pi
    float x2 = x * x;
    float ax2 = a * x2;
    float t = x2 * (c + ax2) * fast_rcp(1.f + ax2);
    float e = __expf(-t);
    float s = __builtin_amdgcn_sqrtf(fmaxf(1.f - e, 0.f));
    return copysignf(s, x);
}

__device__ __forceinline__ float fast_softplus(float x) {
    float t = __expf(-fabsf(x));
    return fmaxf(x, 0.f) + __logf(1.f + t);
}

// ---------------------------------------------------------------------------
// Final conv (9 out ch per group) fused with mixture-CDF -> pmf * 65536
// 4 px per thread. IN origin (y0-2, x0-4), dims (FTH+2)x(FTW+8).
// ---------------------------------------------------------------------------
__global__ __launch_bounds__(256) void final_kernel(
    const float* __restrict__ hbuf, const float* __restrict__ wf,
    const float* __restrict__ bf, float* __restrict__ out)
{
    const int g  = blockIdx.z;
    const int x0 = blockIdx.x * FTW, y0 = blockIdx.y * FTH;
    __shared__ __align__(16) float IN[3][FTH + 2][FTW + 8];
    __shared__ float s_w[9][3][25];
    __shared__ float s_b[9];
    const int tid = threadIdx.y * 16 + threadIdx.x;

    for (int i = tid; i < 675; i += 256) {
        int oc = i / 75, rest = i % 75;
        s_w[oc][rest / 25][rest % 25] =
            wf[((g * 9 + oc) * 3 + rest / 25) * 25 + rest % 25];
    }
    if (tid < 9) s_b[tid] = bf[g * 9 + tid];

    const float* base = hbuf + (size_t)g * 3 * HW;
    for (int i = tid; i < 3 * (FTH + 2) * ((FTW + 8) / 4); i += 256) { // 972
        int ch = i / 324, rem = i % 324, rr = rem / 18, q = rem % 18;
        int gy = y0 - 2 + rr, gx0 = x0 - 4 + 4 * q;
        float4 v = make_float4(0.f, 0.f, 0.f, 0.f);
        if (gy >= 0) {
            const float* rowp = base + (size_t)ch * HW + (size_t)gy * WW;
            if (gx0 >= 0 && gx0 + 3 < WW) {
                v = *(const float4*)(rowp + gx0);
            } else {
                float t[4];
#pragma unroll
                for (int p = 0; p < 4; ++p) {
                    int gx = gx0 + p;
                    t[p] = (gx >= 0 && gx < WW) ? rowp[gx] : 0.f;
                }
                v = make_float4(t[0], t[1], t[2], t[3]);
            }
        }
        *(float4*)&IN[ch][rr][4 * q] = v;
    }
    __syncthreads();

    const int xg = threadIdx.x, yy = threadIdx.y;
    float acc[9][4];
#pragma unroll
    for (int m = 0; m < 9; ++m)
#pragma unroll
        for (int p = 0; p < 4; ++p) acc[m][p] = s_b[m];

#pragma unroll
    for (int ic = 0; ic < 3; ++ic) {
#pragma unroll
        for (int r = 0; r < 3; ++r) {
            float4 u0 = *(const float4*)&IN[ic][yy + r][4 * xg];
            float4 u1 = *(const float4*)&IN[ic][yy + r][4 * xg + 4];
            float4 u2 = *(const float4*)&IN[ic][yy + r][4 * xg + 8];
            float v[12] = {u0.x, u0.y, u0.z, u0.w, u1.x, u1.y, u1.z, u1.w,
                           u2.x, u2.y, u2.z, u2.w};
            const int cmax = (r < 2) ? 5 : 3;
#pragma unroll
            for (int c = 0; c < 5; ++c) {
                if (c >= cmax) break;
#pragma unroll
                for (int m = 0; m < 9; ++m) {
                    float w = s_w[m][ic][r * 5 + c];
#pragma unroll
                    for (int p = 0; p < 4; ++p)
                        acc[m][p] += w * v[c + p + 2];   // IN origin x0-4
                }
            }
        }
    }

    // ---- mixture per pixel ----
    const float inv_sqrt2 = 0.70710678118654752440f;
    float wm0[4], wm1[4], wm2[4], mu0[4], mu1[4], mu2[4], k0[4], k1[4], k2[4];
#pragma unroll
    for (int p = 0; p < 4; ++p) {
        float lw0 = acc[0][p], m0 = acc[1][p], ls0 = acc[2][p];
        float lw1 = acc[3][p], m1 = acc[4][p], ls1 = acc[5][p];
        float lw2 = acc[6][p], m2 = acc[7][p], ls2 = acc[8][p];
        float lmax = fmaxf(lw0, fmaxf(lw1, lw2));
        float e0 = __expf(lw0 - lmax), e1 = __expf(lw1 - lmax), e2 = __expf(lw2 - lmax);
        float inv_sum = fast_rcp(e0 + e1 + e2);
        wm0[p] = 0.5f * e0 * inv_sum;
        wm1[p] = 0.5f * e1 * inv_sum;
        wm2[p] = 0.5f * e2 * inv_sum;
        mu0[p] = m0; mu1[p] = m1; mu2[p] = m2;
        k0[p] = inv_sqrt2 * fast_rcp(fast_softplus(ls0) + 1e-6f);
        k1[p] = inv_sqrt2 * fast_rcp(fast_softplus(ls1) + 1e-6f);
        k2[p] = inv_sqrt2 * fast_rcp(fast_softplus(ls2) + 1e-6f);
    }

    const int gy = y0 + yy;
    float* ob = out + ((size_t)g * 8 * HH + gy) * WW + x0 + 4 * xg;
    float prev[4] = {0.f, 0.f, 0.f, 0.f};
#pragma unroll
    for (int j = 0; j <= 8; ++j) {
        float edge = (float)j - 4.0f;
        float cdf[4];
#pragma unroll
        for (int p = 0; p < 4; ++p) {
            cdf[p] = wm0[p] * (1.f + fast_erf((edge - mu0[p]) * k0[p]))
                   + wm1[p] * (1.f + fast_erf((edge - mu1[p]) * k1[p]))
                   + wm2[p] * (1.f + fast_erf((edge - mu2[p]) * k2[p]));
        }
        if (j > 0) {
            *(float4*)(ob + (size_t)(j - 1) * HW) =
                make_float4((cdf[0] - prev[0]) * 65536.f, (cdf[1] - prev[1]) * 65536.f,
                            (cdf[2] - prev[2]) * 65536.f, (cdf[3] - prev[3]) * 65536.f);
        }
#pragma unroll
        for (int p = 0; p < 4; ++p) prev[p] = cdf[p];
    }
}

// ---------------------------------------------------------------------------
extern "C" void kernel_launch(void* const* d_in, const int* in_sizes, int n_in,
                              void* d_out, int out_size, void* d_ws, size_t ws_size,
                              hipStream_t stream)
{
    const int*   data = (const int*)d_in[0];
    const float* w1   = (const float*)d_in[1];
    const float* b1   = (const float*)d_in[2];
    const float* rw   = (const float*)d_in[3];
    const float* rb   = (const float*)d_in[4];
    const float* wf   = (const float*)d_in[5];
    const float* bf   = (const float*)d_in[6];
    float* out = (float*)d_out;

    float* A = (float*)d_ws;
    float* B = A + (size_t)48 * HW;

    conv1_kernel<<<dim3(6, 96, 16), dim3(64, 4), 0, stream>>>(data, w1, b1, A);

    dim3 blk(16, 16, 1);
    dim3 grd(WW / FTW, HH / FTH, NG);
    const float* cur = A;
    float* nxt = B;
    for (int i = 0; i < 5; ++i) {
        const float* wa = rw + (size_t)(i * 2 + 0) * 48 * 3 * 25;
        const float* ba = rb + (i * 2 + 0) * 48;
        const float* wb = rw + (size_t)(i * 2 + 1) * 48 * 3 * 25;
        const float* bb = rb + (i * 2 + 1) * 48;
        res_block_kernel<<<grd, blk, 0, stream>>>(cur, wa, ba, wb, bb, nxt);
        const float* t = cur; cur = nxt; nxt = (float*)t;
    }
    final_kernel<<<grd, blk, 0, stream>>>(cur, wf, bf, out);
}